// Round 7
// baseline (905.886 us; speedup 1.0000x reference)
//
#include <hip/hip_runtime.h>
#include <hip/hip_bf16.h>

// Problem dims
#define V    50257
#define VPAD 50304          // padded vocab rows for clean 128-tiles (393*128)
#define DD   128
#define HH   256
#define G3   768            // 3*H
#define BB   16
#define TT   128

typedef _Float16 h2   __attribute__((ext_vector_type(2)));
typedef _Float16 h8   __attribute__((ext_vector_type(8)));
typedef short  bf16x8 __attribute__((ext_vector_type(8)));
typedef float  f32x4  __attribute__((ext_vector_type(4)));

typedef __attribute__((address_space(3))) uint4* lds_u4_t;
typedef const __attribute__((address_space(1))) uint4* gbl_u4_t;

__device__ __forceinline__ void async_copy16(const uint4* g, uint4* lds_base) {
    // LDS dest = wave-uniform base + lane*16 (per-lane global scatter is OK)
    __builtin_amdgcn_global_load_lds((gbl_u4_t)g, (lds_u4_t)lds_base, 16, 0, 0);
}

#if __has_builtin(__builtin_amdgcn_fdot2)
#define USE_FDOT2 1
#else
#define USE_FDOT2 0
#endif

__device__ __forceinline__ float sigmoid_(float x) { return 1.0f / (1.0f + __expf(-x)); }
__device__ __forceinline__ float tanh_(float x)    { float e = __expf(2.0f * x); return (e - 1.0f) / (e + 1.0f); }

__device__ __forceinline__ float fdot2_(h2 a, h2 b, float c) {
#if USE_FDOT2
    return __builtin_amdgcn_fdot2(a, b, c, false);
#else
    return c + (float)a.x * (float)b.x + (float)a.y * (float)b.y;
#endif
}

// LDS-only barrier: lgkmcnt(0) (DS ops visible) + raw s_barrier. Crucially
// does NOT drain vmcnt -> global loads/stores stay in flight across steps.
// sched_barrier(0) pins ordering (guide rule #18).
#define BARRIER_LDS() do {                                        \
    asm volatile("s_waitcnt lgkmcnt(0)" ::: "memory");            \
    __builtin_amdgcn_s_barrier();                                 \
    __builtin_amdgcn_sched_barrier(0);                            \
} while (0)

// ---------------------------------------------------------------------------
// Kernel P (merged): blocks [0,256): x = embed[ids]; gx = x @ W_ih^T + b_ih
//                    blocks [256,6544): convert W_out fp32 -> bf16 padded
// ---------------------------------------------------------------------------
__global__ __launch_bounds__(256) void k_prep(
    const int* __restrict__ ids, const float* __restrict__ embed,
    const float* __restrict__ W_ih, const float* __restrict__ b_ih,
    float* __restrict__ gx,
    const float* __restrict__ Wout, __hip_bfloat16* __restrict__ Wb)
{
    __shared__ float xs[8][DD];
    const int tid = threadIdx.x;

    if (blockIdx.x >= 256) {
        // ---- W_out conversion path ----
        long base = ((long)(blockIdx.x - 256) * 256 + tid) * 8;
        const long VALID = (long)V * HH;   // 12,865,792 (divisible by 8)
        union { __hip_bfloat16 b[8]; uint4 u; } pk;
        if (base < VALID) {
            float4 f0 = ((const float4*)Wout)[base / 4];
            float4 f1 = ((const float4*)Wout)[base / 4 + 1];
            pk.b[0] = __float2bfloat16(f0.x); pk.b[1] = __float2bfloat16(f0.y);
            pk.b[2] = __float2bfloat16(f0.z); pk.b[3] = __float2bfloat16(f0.w);
            pk.b[4] = __float2bfloat16(f1.x); pk.b[5] = __float2bfloat16(f1.y);
            pk.b[6] = __float2bfloat16(f1.z); pk.b[7] = __float2bfloat16(f1.w);
        } else {
            pk.u = make_uint4(0, 0, 0, 0);
        }
        *(uint4*)(Wb + base) = pk.u;
        return;
    }

    // ---- embed + gx path ----
    const int row0 = blockIdx.x * 8;

#pragma unroll
    for (int i = 0; i < 4; ++i) {
        int e = tid + i * 256;
        int r = e >> 7, k = e & 127;
        int id = ids[row0 + r];
        xs[r][k] = embed[(long)id * DD + k];
    }
    __syncthreads();

#pragma unroll
    for (int o = 0; o < 3; ++o) {
        int j = tid + o * 256;
        float bias = b_ih[j];
        float acc[8];
#pragma unroll
        for (int r = 0; r < 8; ++r) acc[r] = bias;
        const float4* wrow = (const float4*)(W_ih + (long)j * DD);
        for (int q = 0; q < 32; ++q) {
            float4 w = wrow[q];
#pragma unroll
            for (int r = 0; r < 8; ++r) {
                acc[r] += w.x * xs[r][q * 4 + 0] + w.y * xs[r][q * 4 + 1]
                        + w.z * xs[r][q * 4 + 2] + w.w * xs[r][q * 4 + 3];
            }
        }
#pragma unroll
        for (int r = 0; r < 8; ++r) gx[(long)(row0 + r) * G3 + j] = acc[r];
    }
}

// ---------------------------------------------------------------------------
// Kernel G: GRU recurrence. ROUND-7: eliminate __syncthreads from the loop.
// Diagnosis: ~3400cyc/step is invariant across two radically different
// designs; ruled out = spill/LDS-count/conflicts/barrier-count/stores.
// The never-changed element: __syncthreads forces s_waitcnt vmcnt(0)
// lgkmcnt(0) twice per step with all waves lockstep -> per-step gx L3-load
// (~500-900cy) + LDS round-trips + barriers are serialized, never hidden.
// Fix (T3/T4 pattern): gx chunk-staged into LDS via global_load_lds, one
// chunk ahead, counted s_waitcnt vmcnt(2) at chunk boundaries (never 0 in
// the loop); per-step sync is raw s_barrier + lgkmcnt(0) only, so global
// traffic stays in flight across steps.
// DIAGNOSTIC: 2 passes (h reset per pass, identical output). If fix works:
// dur ~700 (drop pass 2 next round). If null: dur ~940 and k_gru surfaces
// in top-5 with warm counters. G_new = (dur - 586) / 2.
// ---------------------------------------------------------------------------
#define CH   8      // steps per gx chunk
#define NCH  16     // chunks (CH*NCH = TT)

__global__ __launch_bounds__(768)
__attribute__((amdgpu_waves_per_eu(3, 3)))
void k_gru(
    const float* __restrict__ gx, const float* __restrict__ W_hh,
    const float* __restrict__ b_hh, __hip_bfloat16* __restrict__ hout)
{
    __shared__ float     gxs[2][CH][G3];   // 48 KB double-buffered gx chunks
    __shared__ _Float16  hhs[HH];          // current hidden state (f16)
    __shared__ float     ghs[G3];          // per-step gate pre-activations

    const int j  = threadIdx.x;     // [0,768) = W_hh row
    const int b  = blockIdx.x;      // batch
    const int wv = j >> 6;          // wave [0,12)
    const int ln = j & 63;          // lane

    // one-time: this thread's full W_hh row -> 128 h2 regs.
    h2 w[128];
    const float4* wr = (const float4*)(W_hh + (long)j * HH);
#pragma unroll
    for (int qq = 0; qq < 8; ++qq) {
        float4 f[8];
#pragma unroll
        for (int q = 0; q < 8; ++q) f[q] = wr[qq * 8 + q];
        asm volatile("" ::: "memory");
#pragma unroll
        for (int q = 0; q < 8; ++q) {
            w[qq * 16 + 2 * q]     = h2{(_Float16)f[q].x, (_Float16)f[q].y};
            w[qq * 16 + 2 * q + 1] = h2{(_Float16)f[q].z, (_Float16)f[q].w};
        }
    }
    const float bias = b_hh[j];

    const float* gxb = gx + (long)b * TT * G3;

    // stage chunk c into buffer buf: 24KB, 2 x 1KB per wave (12 waves)
    auto stage = [&](int c, int buf) {
        const uint4* src = (const uint4*)(gxb + (long)c * CH * G3);
        uint4* dstb = (uint4*)(&gxs[buf][0][0]);
        async_copy16(src + (wv * 2 + 0) * 64 + ln, dstb + (wv * 2 + 0) * 64);
        async_copy16(src + (wv * 2 + 1) * 64 + ln, dstb + (wv * 2 + 1) * 64);
    };

    for (int pass = 0; pass < 2; ++pass) {   // DIAGNOSTIC x2 (identical output)
        if (j < HH) hhs[j] = (_Float16)0.0f;
        float hold = 0.0f;
        stage(0, 0);

        for (int c = 0; c < NCH; ++c) {
            const int buf = c & 1;
            if (c + 1 < NCH) {
                stage(c + 1, buf ^ 1);
                // all but the 2 newest VMEM ops done => chunk c staged,
                // prior hout stores retired. NEVER vmcnt(0) mid-loop.
                asm volatile("s_waitcnt vmcnt(2)" ::: "memory");
            } else {
                asm volatile("s_waitcnt vmcnt(0)" ::: "memory");
            }
            BARRIER_LDS();   // chunk c visible to all waves (+ hhs init at c=0)

            for (int s = 0; s < CH; ++s) {
                const int t = c * CH + s;
                float xr = 0.f, xz = 0.f, xn = 0.f;
                if (j < HH) {
                    xr = gxs[buf][s][j];
                    xz = gxs[buf][s][HH + j];
                    xn = gxs[buf][s][2 * HH + j];
                }

                // dot(W[j], h): 32 b128 broadcast reads, chunked 4-at-a-time
                float da = 0.f, db = 0.f;
                const h8* hp8 = (const h8*)hhs;
#pragma unroll
                for (int cc = 0; cc < 8; ++cc) {
                    h8 hv0 = hp8[cc * 4 + 0];
                    h8 hv1 = hp8[cc * 4 + 1];
                    h8 hv2 = hp8[cc * 4 + 2];
                    h8 hv3 = hp8[cc * 4 + 3];
                    asm volatile("" ::: "memory");
                    const h8 hvs[4] = {hv0, hv1, hv2, hv3};
#pragma unroll
                    for (int c2 = 0; c2 < 4; ++c2) {
                        const h2* hp = (const h2*)&hvs[c2];
#pragma unroll
                        for (int jj = 0; jj < 4; ++jj) {
                            int p = cc * 16 + c2 * 4 + jj;
                            if (jj & 1) db = fdot2_(w[p], hp[jj], db);
                            else        da = fdot2_(w[p], hp[jj], da);
                        }
                    }
                }
                ghs[j] = da + db + bias;
                BARRIER_LDS();          // ghs ready; hhs reads drained (WAR)

                if (j < HH) {
                    float r = sigmoid_(xr + ghs[j]);
                    float z = sigmoid_(xz + ghs[HH + j]);
                    float n = tanh_(xn + r * ghs[2 * HH + j]);
                    float hnew = (1.0f - z) * n + z * hold;
                    hold = hnew;
                    hhs[j] = (_Float16)hnew;
                    hout[((long)b * TT + t) * HH + j] = __float2bfloat16(hnew);
                }
                BARRIER_LDS();          // hhs[t+1] visible; stores stay in flight
            }
        }
    }
}

// ---------------------------------------------------------------------------
// Kernel C: LM head GEMM. C[2048,50257] = A[2048,256] * B[50304,256]^T, bf16
// MFMA 16x16x32, BM=BN=128, BK=64, 256 threads (4 waves, 2x2 of 64x64).
// (round-3/5 configuration: XCD-aligned 1-D grid; measured H ~= 165us)
// ---------------------------------------------------------------------------
__global__ __launch_bounds__(256) void k_head(
    const __hip_bfloat16* __restrict__ Ah, const __hip_bfloat16* __restrict__ Bw,
    float* __restrict__ out)
{
    __shared__ unsigned short As[128 * 64];
    __shared__ unsigned short Bs[128 * 64];
    const int i    = threadIdx.x;
    const int wave = i >> 6, lane = i & 63;
    const int quad = lane >> 4, mr = lane & 15;

    // XCD-aligned tile assignment: lid%8 == ntile%8 (bijective over valid tiles)
    const int lid = blockIdx.x;          // [0, 6400)
    const int xq  = lid & 7;
    const int j   = lid >> 3;            // [0, 800)
    const int nt  = xq + 8 * (j % 50);   // n-tile, nt%8 == lid%8
    if (nt >= 393) return;               // 112 pad blocks idle
    const int m0  = (j / 50) * 128;
    const int n0  = nt * 128;

    const int wm0  = (wave >> 1) * 64;
    const int wn0  = (wave & 1) * 64;

    f32x4 acc[4][4];
#pragma unroll
    for (int a = 0; a < 4; ++a)
#pragma unroll
        for (int c = 0; c < 4; ++c) acc[a][c] = (f32x4){0.f, 0.f, 0.f, 0.f};

    const uint4* Ag = (const uint4*)Ah;   // row = 32 uint4 (256 bf16)
    const uint4* Bg = (const uint4*)Bw;
    uint4* Asv = (uint4*)As;
    uint4* Bsv = (uint4*)Bs;

    // Precompute per-lane global base addresses + wave-uniform LDS bases.
    // Segment seg = c*4 + wave covers LDS slots [seg*64, seg*64+64).
    const uint4* agp[4]; const uint4* bgp[4];
    uint4* alds[4]; uint4* blds[4];
#pragma unroll
    for (int c = 0; c < 4; ++c) {
        int seg   = c * 4 + wave;
        int row   = seg * 8 + (lane >> 3);
        int chunk = (lane & 7) ^ (row & 7);
        agp[c] = Ag + (long)(m0 + row) * 32 + chunk;
        bgp[c] = Bg + (long)(n0 + row) * 32 + chunk;
        alds[c] = Asv + seg * 64;   // + lane*16B implicit in global_load_lds
        blds[c] = Bsv + seg * 64;
    }

    for (int ks = 0; ks < 4; ++ks) {
        __syncthreads();   // previous iteration's LDS readers done
#pragma unroll
        for (int c = 0; c < 4; ++c) async_copy16(agp[c] + ks * 8, alds[c]);
#pragma unroll
        for (int c = 0; c < 4; ++c) async_copy16(bgp[c] + ks * 8, blds[c]);
        __syncthreads();   // compiler emits s_waitcnt vmcnt(0) before barrier

#pragma unroll
        for (int kk = 0; kk < 2; ++kk) {
            bf16x8 af[4], bf[4];
#pragma unroll
            for (int wmi = 0; wmi < 4; ++wmi) {
                int row  = wm0 + wmi * 16 + mr;
                int slot = (kk * 4 + quad) ^ (row & 7);
                af[wmi] = *(const bf16x8*)&As[(row * 8 + slot) * 8];
            }
#pragma unroll
            for (int wni = 0; wni < 4; ++wni) {
                int row  = wn0 + wni * 16 + mr;
                int slot = (kk * 4 + quad) ^ (row & 7);
                bf[wni] = *(const bf16x8*)&Bs[(row * 8 + slot) * 8];
            }
#pragma unroll
            for (int wmi = 0; wmi < 4; ++wmi)
#pragma unroll
                for (int wni = 0; wni < 4; ++wni)
                    acc[wmi][wni] = __builtin_amdgcn_mfma_f32_16x16x32_bf16(
                        af[wmi], bf[wni], acc[wmi][wni], 0, 0, 0);
        }
    }

    // epilogue: C/D layout col = lane&15, row = quad*4 + reg
#pragma unroll
    for (int wmi = 0; wmi < 4; ++wmi) {
#pragma unroll
        for (int rr = 0; rr < 4; ++rr) {
            long m = m0 + wm0 + wmi * 16 + quad * 4 + rr;
            float* orow = out + m * (long)V;
#pragma unroll
            for (int wni = 0; wni < 4; ++wni) {
                int n = n0 + wn0 + wni * 16 + mr;
                if (n < V) orow[n] = acc[wmi][wni][rr];
            }
        }
    }
}

// ---------------------------------------------------------------------------
extern "C" void kernel_launch(void* const* d_in, const int* in_sizes, int n_in,
                              void* d_out, int out_size, void* d_ws, size_t ws_size,
                              hipStream_t stream) {
    const int*   ids   = (const int*)d_in[0];
    const float* embed = (const float*)d_in[1];
    const float* W_ih  = (const float*)d_in[2];
    const float* b_ih  = (const float*)d_in[3];
    const float* W_hh  = (const float*)d_in[4];
    const float* b_hh  = (const float*)d_in[5];
    const float* W_out = (const float*)d_in[6];
    float* out = (float*)d_out;

    // workspace layout (ws re-poisoned each launch; everything rewritten here)
    char* ws = (char*)d_ws;
    float*          gx  = (float*)ws;                           // 2048*768*4   = 6,291,456 B
    __hip_bfloat16* hbf = (__hip_bfloat16*)(ws + 6291456);      // 2048*256*2   = 1,048,576 B
    __hip_bfloat16* wbf = (__hip_bfloat16*)(ws + 7340032);      // 50304*256*2  = 25,755,648 B

    k_prep<<<6544, 256, 0, stream>>>(ids, embed, W_ih, b_ih, gx, W_out, wbf);
    k_gru<<<16, 768, 0, stream>>>(gx, W_hh, b_hh, hbf);
    k_head<<<6400, 256, 0, stream>>>(hbf, wbf, out);
}

// Round 8
// 731.407 us; speedup vs baseline: 1.2386x; 1.2386x over previous
//
#include <hip/hip_runtime.h>
#include <hip/hip_bf16.h>

// Problem dims
#define V    50257
#define VPAD 50304          // padded vocab rows for clean 128-tiles (393*128)
#define DD   128
#define HH   256
#define G3   768            // 3*H
#define BB   16
#define TT   128

typedef _Float16 h2   __attribute__((ext_vector_type(2)));
typedef _Float16 h8   __attribute__((ext_vector_type(8)));
typedef short  bf16x8 __attribute__((ext_vector_type(8)));
typedef float  f32x4  __attribute__((ext_vector_type(4)));

typedef __attribute__((address_space(3))) uint4* lds_u4_t;
typedef const __attribute__((address_space(1))) uint4* gbl_u4_t;

__device__ __forceinline__ void async_copy16(const uint4* g, uint4* lds_base) {
    // LDS dest = wave-uniform base + lane*16 (per-lane global scatter is OK)
    __builtin_amdgcn_global_load_lds((gbl_u4_t)g, (lds_u4_t)lds_base, 16, 0, 0);
}

#if __has_builtin(__builtin_amdgcn_fdot2)
#define USE_FDOT2 1
#else
#define USE_FDOT2 0
#endif

__device__ __forceinline__ float sigmoid_(float x) { return 1.0f / (1.0f + __expf(-x)); }
__device__ __forceinline__ float tanh_(float x)    { float e = __expf(2.0f * x); return (e - 1.0f) / (e + 1.0f); }

__device__ __forceinline__ float fdot2_(h2 a, h2 b, float c) {
#if USE_FDOT2
    return __builtin_amdgcn_fdot2(a, b, c, false);
#else
    return c + (float)a.x * (float)b.x + (float)a.y * (float)b.y;
#endif
}

// LDS-only barrier: lgkmcnt(0) (DS ops visible) + raw s_barrier. Does NOT
// drain vmcnt -> global loads/stores stay in flight across steps.
#define BARRIER_LDS() do {                                        \
    asm volatile("s_waitcnt lgkmcnt(0)" ::: "memory");            \
    __builtin_amdgcn_s_barrier();                                 \
    __builtin_amdgcn_sched_barrier(0);                            \
} while (0)

// ---------------------------------------------------------------------------
// Kernel P (merged): blocks [0,256):      x = embed[ids]; gx = x@W_ih^T + b_ih
//                    blocks [256,6544):   W_out fp32 -> bf16 padded
//                    blocks [6544,6640):  W_hh  fp32 -> f16 row-major
// The W_hh pre-conversion removes ALL fp32->f16 conversion work from k_gru's
// steady state (round-7 rocprof: VGPR=84 + VALUBusy 55% on active CUs =
// compiler remat'ing the conversions every timestep instead of keeping W
// register-resident).
// ---------------------------------------------------------------------------
__global__ __launch_bounds__(256) void k_prep(
    const int* __restrict__ ids, const float* __restrict__ embed,
    const float* __restrict__ W_ih, const float* __restrict__ b_ih,
    float* __restrict__ gx,
    const float* __restrict__ Wout, __hip_bfloat16* __restrict__ Wb,
    const float* __restrict__ W_hh, _Float16* __restrict__ Wh)
{
    __shared__ float xs[8][DD];
    const int tid = threadIdx.x;

    if (blockIdx.x >= 6544) {
        // ---- W_hh fp32 -> f16 path: 96 blocks x 256 thr x 8 = 196608 exact --
        long base = ((long)(blockIdx.x - 6544) * 256 + tid) * 8;
        float4 f0 = ((const float4*)W_hh)[base / 4];
        float4 f1 = ((const float4*)W_hh)[base / 4 + 1];
        union { _Float16 h[8]; uint4 u; } pk;
        pk.h[0] = (_Float16)f0.x; pk.h[1] = (_Float16)f0.y;
        pk.h[2] = (_Float16)f0.z; pk.h[3] = (_Float16)f0.w;
        pk.h[4] = (_Float16)f1.x; pk.h[5] = (_Float16)f1.y;
        pk.h[6] = (_Float16)f1.z; pk.h[7] = (_Float16)f1.w;
        *(uint4*)(Wh + base) = pk.u;
        return;
    }

    if (blockIdx.x >= 256) {
        // ---- W_out conversion path ----
        long base = ((long)(blockIdx.x - 256) * 256 + tid) * 8;
        const long VALID = (long)V * HH;   // 12,865,792 (divisible by 8)
        union { __hip_bfloat16 b[8]; uint4 u; } pk;
        if (base < VALID) {
            float4 f0 = ((const float4*)Wout)[base / 4];
            float4 f1 = ((const float4*)Wout)[base / 4 + 1];
            pk.b[0] = __float2bfloat16(f0.x); pk.b[1] = __float2bfloat16(f0.y);
            pk.b[2] = __float2bfloat16(f0.z); pk.b[3] = __float2bfloat16(f0.w);
            pk.b[4] = __float2bfloat16(f1.x); pk.b[5] = __float2bfloat16(f1.y);
            pk.b[6] = __float2bfloat16(f1.z); pk.b[7] = __float2bfloat16(f1.w);
        } else {
            pk.u = make_uint4(0, 0, 0, 0);
        }
        *(uint4*)(Wb + base) = pk.u;
        return;
    }

    // ---- embed + gx path ----
    const int row0 = blockIdx.x * 8;

#pragma unroll
    for (int i = 0; i < 4; ++i) {
        int e = tid + i * 256;
        int r = e >> 7, k = e & 127;
        int id = ids[row0 + r];
        xs[r][k] = embed[(long)id * DD + k];
    }
    __syncthreads();

#pragma unroll
    for (int o = 0; o < 3; ++o) {
        int j = tid + o * 256;
        float bias = b_ih[j];
        float acc[8];
#pragma unroll
        for (int r = 0; r < 8; ++r) acc[r] = bias;
        const float4* wrow = (const float4*)(W_ih + (long)j * DD);
        for (int q = 0; q < 32; ++q) {
            float4 w = wrow[q];
#pragma unroll
            for (int r = 0; r < 8; ++r) {
                acc[r] += w.x * xs[r][q * 4 + 0] + w.y * xs[r][q * 4 + 1]
                        + w.z * xs[r][q * 4 + 2] + w.w * xs[r][q * 4 + 3];
            }
        }
#pragma unroll
        for (int r = 0; r < 8; ++r) gx[(long)(row0 + r) * G3 + j] = acc[r];
    }
}

// ---------------------------------------------------------------------------
// Kernel G: GRU recurrence, ROUND-8.
// Root cause (r7 rocprof): W was NEVER register-resident (VGPR=84 vs 128+
// demanded). Two causes killed promotion: (a) my asm "memory" fences block
// SROA -> the w[] alloca stays in scratch; (b) fp32->f16 conversion gives the
// compiler a cheap remat path (re-converting each step = the measured 55%
// VALUBusy). Fix: pre-converted f16 W (no conversions, no fences, constant
// indices only -> clean promotion) + 512 threads / K-split-2 so demand
// (~230) sits comfortably under the waves_per_eu(2,2) budget of 256.
// Structure kept from r7: gx chunk-staged via global_load_lds one chunk
// ahead, counted s_waitcnt vmcnt(3) (never 0 mid-loop), LDS-only barriers,
// ONE barrier/step (double-buffered h, shfl pair-reduce, no ghs round-trip).
// ---------------------------------------------------------------------------
#define CH   8      // steps per gx chunk
#define NCH  16     // chunks (CH*NCH = TT)

__global__ __launch_bounds__(512)
__attribute__((amdgpu_waves_per_eu(2, 2)))
void k_gru(
    const float* __restrict__ gx, const _Float16* __restrict__ Wh,
    const float* __restrict__ b_hh, __hip_bfloat16* __restrict__ hout)
{
    __shared__ float    gxs[2][CH][G3];   // 48 KB double-buffered gx chunks
    __shared__ _Float16 hh[2][HH];        // double-buffered hidden state

    const int tid = threadIdx.x;
    const int b   = blockIdx.x;      // batch
    const int g   = tid >> 1;        // output row within each gate [0,256)
    const int u   = tid & 1;         // K-half
    const int wv  = tid >> 6;        // wave [0,8)
    const int ln  = tid & 63;        // lane

    // W_hh rows {g, 256+g, 512+g}, K-half u: 3 x 16 h8 = 192 VGPRs.
    // Plain vector loads from pre-converted f16, constant indices, NO fences.
    h8 w8[3][16];
#pragma unroll
    for (int o = 0; o < 3; ++o) {
        const h8* wrow = (const h8*)(Wh + (long)(o * HH + g) * HH + u * 128);
#pragma unroll
        for (int q = 0; q < 16; ++q) w8[o][q] = wrow[q];
    }
    float bias[3];
#pragma unroll
    for (int o = 0; o < 3; ++o) bias[o] = b_hh[o * HH + g];

    if (tid < HH) hh[0][tid] = (_Float16)0.0f;

    const float* gxb = gx + (long)b * TT * G3;
    // stage chunk c (24KB = 1536 uint4) into buffer buf: 3 x 64 lanes per wave
    auto stage = [&](int c, int buf) {
        const uint4* src = (const uint4*)(gxb + (long)c * CH * G3);
        uint4* dstb = (uint4*)(&gxs[buf][0][0]);
#pragma unroll
        for (int k = 0; k < 3; ++k)
            async_copy16(src + (wv * 3 + k) * 64 + ln, dstb + (wv * 3 + k) * 64);
    };

    stage(0, 0);
    float hold = 0.0f;

    for (int c = 0; c < NCH; ++c) {
        const int buf = c & 1;
        if (c + 1 < NCH) {
            stage(c + 1, buf ^ 1);
            // wait until only the 3 newest VMEM ops (next-chunk stage) remain:
            // chunk c is staged AND this wave's prior hout stores are retired.
            asm volatile("s_waitcnt vmcnt(3)" ::: "memory");
        } else {
            asm volatile("s_waitcnt vmcnt(0)" ::: "memory");
        }
        BARRIER_LDS();   // chunk c visible (+ hh[0] init at c=0)

        for (int s = 0; s < CH; ++s) {
            const int t = c * CH + s;
            // gx reads: lanes 2g,2g+1 same address -> LDS broadcast
            float xr = gxs[buf][s][g];
            float xz = gxs[buf][s][HH + g];
            float xn = gxs[buf][s][2 * HH + g];

            // dot over this thread's K-half: 3 gates x 64 h2, 2 acc chains
            float a0a = 0.f, a0b = 0.f, a1a = 0.f, a1b = 0.f, a2a = 0.f, a2b = 0.f;
            const h8* hp8 = ((const h8*)hh[t & 1]) + u * 16;
#pragma unroll
            for (int q = 0; q < 16; ++q) {
                h8 hv = hp8[q];
                const h2* hq = (const h2*)&hv;
                const h2* w0 = (const h2*)&w8[0][q];
                const h2* w1 = (const h2*)&w8[1][q];
                const h2* w2 = (const h2*)&w8[2][q];
#pragma unroll
                for (int jj = 0; jj < 4; ++jj) {
                    if (jj & 1) {
                        a0b = fdot2_(w0[jj], hq[jj], a0b);
                        a1b = fdot2_(w1[jj], hq[jj], a1b);
                        a2b = fdot2_(w2[jj], hq[jj], a2b);
                    } else {
                        a0a = fdot2_(w0[jj], hq[jj], a0a);
                        a1a = fdot2_(w1[jj], hq[jj], a1a);
                        a2a = fdot2_(w2[jj], hq[jj], a2a);
                    }
                }
            }
            float acc0 = a0a + a0b, acc1 = a1a + a1b, acc2 = a2a + a2b;
            // pair reduce (lanes 2g, 2g+1 in same wave)
            acc0 += __shfl_xor(acc0, 1);
            acc1 += __shfl_xor(acc1, 1);
            acc2 += __shfl_xor(acc2, 1);

            float r = sigmoid_(xr + acc0 + bias[0]);
            float z = sigmoid_(xz + acc1 + bias[1]);
            float n = tanh_(xn + r * (acc2 + bias[2]));
            float hnew = (1.0f - z) * n + z * hold;

            // u==0 writes next h buffer; u==1 writes bf16 output (in parallel).
            // hout store is NOT drained here (LDS-only barrier) -> retires in
            // the background, forced done once per chunk by vmcnt(3).
            if (u == 0) hh[(t + 1) & 1][g] = (_Float16)hnew;
            else        hout[((long)b * TT + t) * HH + g] = __float2bfloat16(hnew);
            BARRIER_LDS();   // next h buffer ready; one barrier per step

            hold = hnew;
        }
    }
}

// ---------------------------------------------------------------------------
// Kernel C: LM head GEMM. C[2048,50257] = A[2048,256] * B[50304,256]^T, bf16
// MFMA 16x16x32, BM=BN=128, BK=64, 256 threads (4 waves, 2x2 of 64x64).
// (round-3/5 configuration, byte-identical: XCD-aligned 1-D grid; H ~= 165us)
// ---------------------------------------------------------------------------
__global__ __launch_bounds__(256) void k_head(
    const __hip_bfloat16* __restrict__ Ah, const __hip_bfloat16* __restrict__ Bw,
    float* __restrict__ out)
{
    __shared__ unsigned short As[128 * 64];
    __shared__ unsigned short Bs[128 * 64];
    const int i    = threadIdx.x;
    const int wave = i >> 6, lane = i & 63;
    const int quad = lane >> 4, mr = lane & 15;

    // XCD-aligned tile assignment: lid%8 == ntile%8 (bijective over valid tiles)
    const int lid = blockIdx.x;          // [0, 6400)
    const int xq  = lid & 7;
    const int j   = lid >> 3;            // [0, 800)
    const int nt  = xq + 8 * (j % 50);   // n-tile, nt%8 == lid%8
    if (nt >= 393) return;               // 112 pad blocks idle
    const int m0  = (j / 50) * 128;
    const int n0  = nt * 128;

    const int wm0  = (wave >> 1) * 64;
    const int wn0  = (wave & 1) * 64;

    f32x4 acc[4][4];
#pragma unroll
    for (int a = 0; a < 4; ++a)
#pragma unroll
        for (int c = 0; c < 4; ++c) acc[a][c] = (f32x4){0.f, 0.f, 0.f, 0.f};

    const uint4* Ag = (const uint4*)Ah;   // row = 32 uint4 (256 bf16)
    const uint4* Bg = (const uint4*)Bw;
    uint4* Asv = (uint4*)As;
    uint4* Bsv = (uint4*)Bs;

    // Precompute per-lane global base addresses + wave-uniform LDS bases.
    // Segment seg = c*4 + wave covers LDS slots [seg*64, seg*64+64).
    const uint4* agp[4]; const uint4* bgp[4];
    uint4* alds[4]; uint4* blds[4];
#pragma unroll
    for (int c = 0; c < 4; ++c) {
        int seg   = c * 4 + wave;
        int row   = seg * 8 + (lane >> 3);
        int chunk = (lane & 7) ^ (row & 7);
        agp[c] = Ag + (long)(m0 + row) * 32 + chunk;
        bgp[c] = Bg + (long)(n0 + row) * 32 + chunk;
        alds[c] = Asv + seg * 64;   // + lane*16B implicit in global_load_lds
        blds[c] = Bsv + seg * 64;
    }

    for (int ks = 0; ks < 4; ++ks) {
        __syncthreads();   // previous iteration's LDS readers done
#pragma unroll
        for (int c = 0; c < 4; ++c) async_copy16(agp[c] + ks * 8, alds[c]);
#pragma unroll
        for (int c = 0; c < 4; ++c) async_copy16(bgp[c] + ks * 8, blds[c]);
        __syncthreads();   // compiler emits s_waitcnt vmcnt(0) before barrier

#pragma unroll
        for (int kk = 0; kk < 2; ++kk) {
            bf16x8 af[4], bf[4];
#pragma unroll
            for (int wmi = 0; wmi < 4; ++wmi) {
                int row  = wm0 + wmi * 16 + mr;
                int slot = (kk * 4 + quad) ^ (row & 7);
                af[wmi] = *(const bf16x8*)&As[(row * 8 + slot) * 8];
            }
#pragma unroll
            for (int wni = 0; wni < 4; ++wni) {
                int row  = wn0 + wni * 16 + mr;
                int slot = (kk * 4 + quad) ^ (row & 7);
                bf[wni] = *(const bf16x8*)&Bs[(row * 8 + slot) * 8];
            }
#pragma unroll
            for (int wmi = 0; wmi < 4; ++wmi)
#pragma unroll
                for (int wni = 0; wni < 4; ++wni)
                    acc[wmi][wni] = __builtin_amdgcn_mfma_f32_16x16x32_bf16(
                        af[wmi], bf[wni], acc[wmi][wni], 0, 0, 0);
        }
    }

    // epilogue: C/D layout col = lane&15, row = quad*4 + reg
#pragma unroll
    for (int wmi = 0; wmi < 4; ++wmi) {
#pragma unroll
        for (int rr = 0; rr < 4; ++rr) {
            long m = m0 + wm0 + wmi * 16 + quad * 4 + rr;
            float* orow = out + m * (long)V;
#pragma unroll
            for (int wni = 0; wni < 4; ++wni) {
                int n = n0 + wn0 + wni * 16 + mr;
                if (n < V) orow[n] = acc[wmi][wni][rr];
            }
        }
    }
}

// ---------------------------------------------------------------------------
extern "C" void kernel_launch(void* const* d_in, const int* in_sizes, int n_in,
                              void* d_out, int out_size, void* d_ws, size_t ws_size,
                              hipStream_t stream) {
    const int*   ids   = (const int*)d_in[0];
    const float* embed = (const float*)d_in[1];
    const float* W_ih  = (const float*)d_in[2];
    const float* b_ih  = (const float*)d_in[3];
    const float* W_hh  = (const float*)d_in[4];
    const float* b_hh  = (const float*)d_in[5];
    const float* W_out = (const float*)d_in[6];
    float* out = (float*)d_out;

    // workspace layout (ws re-poisoned each launch; everything rewritten here)
    char* ws = (char*)d_ws;
    float*          gx   = (float*)ws;                          // 2048*768*4   = 6,291,456 B
    __hip_bfloat16* hbf  = (__hip_bfloat16*)(ws + 6291456);     // 2048*256*2   = 1,048,576 B
    __hip_bfloat16* wbf  = (__hip_bfloat16*)(ws + 7340032);     // 50304*256*2  = 25,755,648 B
    _Float16*       wh16 = (_Float16*)(ws + 33095680);          // 768*256*2    = 393,216 B

    k_prep<<<6640, 256, 0, stream>>>(ids, embed, W_ih, b_ih, gx, W_out, wbf, W_hh, wh16);
    k_gru<<<16, 512, 0, stream>>>(gx, wh16, b_hh, hbf);
    k_head<<<6400, 256, 0, stream>>>(hbf, wbf, out);
}